// Round 5
// baseline (772.977 us; speedup 1.0000x reference)
//
#include <hip/hip_runtime.h>
#include <hip/hip_bf16.h>

#define NB   64     // batch
#define NS   128    // seq len
#define ND   256    // embed dim
#define NU   512    // hidden units
#define N3   1536   // 3*NU

typedef __attribute__((ext_vector_type(4))) float  f32x4;
typedef __attribute__((ext_vector_type(8))) short  s16x8;
typedef unsigned long long u64;
typedef unsigned int       u32;
typedef unsigned short     u16;

__device__ __forceinline__ u16 f2bf(float v) {
  unsigned u = __builtin_bit_cast(unsigned, v);
  u += 0x7fffu + ((u >> 16) & 1u);          // round-to-nearest-even
  return (u16)(u >> 16);
}

// -------- init: hx[0] = bf16(hidden); zero step counters (graph-replay safe) ---
__global__ void init_kernel(const float* __restrict__ hidden,
                            u16* __restrict__ hx,
                            u32* __restrict__ cnt) {
  const int b = blockIdx.x, u = threadIdx.x;   // 64 x 512
  hx[b * NU + u] = f2bf(hidden[b * NU + u]);
  const int i = b * NU + u;
  if (i < 4 * NS) cnt[i] = 0u;                 // 4 groups * 128 steps
}

// -------- phase 1: xp = gather(emb,x) @ W + b_in  (f32 SIMT, unchanged) --------
__global__ __launch_bounds__(256) void xproj_kernel(
    const int* __restrict__ x, const float* __restrict__ emb,
    const float* __restrict__ W, const float* __restrict__ bias,
    float* __restrict__ xp) {
  __shared__ float As[32][68];
  __shared__ float Bs[32][68];
  __shared__ int tok[64];
  const int tid = threadIdx.x;
  const int m0 = blockIdx.y * 64;
  const int n0 = blockIdx.x * 64;
  if (tid < 64) tok[tid] = x[m0 + tid];
  __syncthreads();
  const int tx = tid & 15, ty = tid >> 4;
  float acc[4][4] = {};
  for (int k0 = 0; k0 < ND; k0 += 32) {
    {
      const int m = tid & 63, kq = tid >> 6;
      const float* src = emb + (size_t)tok[m] * ND + k0 + kq * 8;
      const float4 v0 = *(const float4*)(src);
      const float4 v1 = *(const float4*)(src + 4);
      As[kq*8+0][m] = v0.x; As[kq*8+1][m] = v0.y;
      As[kq*8+2][m] = v0.z; As[kq*8+3][m] = v0.w;
      As[kq*8+4][m] = v1.x; As[kq*8+5][m] = v1.y;
      As[kq*8+6][m] = v1.z; As[kq*8+7][m] = v1.w;
    }
    {
      const int n = (tid & 15) * 4, k = tid >> 4;
      *(float4*)&Bs[k][n]    = *(const float4*)&W[(size_t)(k0 + k) * N3 + n0 + n];
      *(float4*)&Bs[k+16][n] = *(const float4*)&W[(size_t)(k0 + k + 16) * N3 + n0 + n];
    }
    __syncthreads();
    #pragma unroll
    for (int kk = 0; kk < 32; ++kk) {
      const float4 b4 = *(const float4*)&Bs[kk][tx * 4];
      float a[4];
      #pragma unroll
      for (int i = 0; i < 4; ++i) a[i] = As[kk][ty * 4 + i];
      #pragma unroll
      for (int i = 0; i < 4; ++i) {
        acc[i][0] += a[i] * b4.x;
        acc[i][1] += a[i] * b4.y;
        acc[i][2] += a[i] * b4.z;
        acc[i][3] += a[i] * b4.w;
      }
    }
    __syncthreads();
  }
  #pragma unroll
  for (int i = 0; i < 4; ++i) {
    const size_t row = (size_t)(m0 + ty * 4 + i) * N3 + n0 + tx * 4;
    float4 o;
    o.x = acc[i][0] + bias[n0 + tx*4 + 0];
    o.y = acc[i][1] + bias[n0 + tx*4 + 1];
    o.z = acc[i][2] + bias[n0 + tx*4 + 2];
    o.w = acc[i][3] + bias[n0 + tx*4 + 3];
    *(float4*)&xp[row] = o;
  }
}

// -------- phase 2: persistent GRU scan, barrier-free dataflow ------------------
// 64 blocks = 4 batch-groups (16 batches) x 16 unit-blocks (32 units); each wave
// owns 16 units end-to-end (gates read MFMA accumulators directly).
// Sync per (group,step): each wave atomicAdds one shared counter (no-return add,
// pipelined at the LLC); consumers poll the counter with a WAVE-UNIFORM load so
// the whole wave issues ONE LLC request per poll iteration (32 in flight per
// group instead of 512 -> no line contention).
__global__ __launch_bounds__(128) void gru_scan_kernel(
    const float* __restrict__ xp, const float* __restrict__ hidden,
    const float* __restrict__ R, const float* __restrict__ bias,
    float* __restrict__ out, u16* __restrict__ hx,
    u32* __restrict__ cnt) {
  __shared__ u16 Rt[96][520];   // [c][k]: c = wv*48 + gate*16 + cu

  const int bid = blockIdx.x;
  const int g   = bid >> 4;          // batch group 0..3
  const int u0  = (bid & 15) * 32;   // unit base of this block
  const int tid = threadIdx.x;
  const int lane = tid & 63;
  const int wv   = tid >> 6;

  // one-time: stage R columns transposed to bf16, remapped per-wave
  for (int idx = tid; idx < 512 * 128; idx += 128) {
    const int k = idx >> 7, c = idx & 127;
    if (c < 96) {
      const int wc = c / 48, r = c % 48, j = r >> 4, cuu = r & 15;
      Rt[c][k] = f2bf(R[(size_t)k * N3 + (j << 9) + u0 + (wc << 4) + cuu]);
    }
  }
  __syncthreads();

  const int ar  = lane & 15;          // A row (batch within group)
  const int kg  = lane >> 4;          // k-group
  const int cu  = lane & 15;          // unit within wave slice
  const int myu = u0 + (wv << 4) + cu;   // my global unit
  const int drow = kg << 2;           // batch base for D rows
  const int cb  = wv * 48 + cu;       // Rt row base (gate tile j at cb + 16j)

  const float bz = bias[N3 + myu];
  const float br = bias[N3 + 512 + myu];
  const float bh = bias[N3 + 1024 + myu];

  float hr[4];
  #pragma unroll
  for (int i = 0; i < 4; ++i)
    hr[i] = hidden[(size_t)((g << 4) + drow + i) * NU + myu];

  for (int t = 0; t < NS; ++t) {
    // xp prefetch: 4 batches x 3 gates, my unit (issued before the poll)
    float xg0[4], xg1[4], xg2[4];
    #pragma unroll
    for (int i = 0; i < 4; ++i) {
      const float* q = xp + ((size_t)(((g << 4) + drow + i) * NS) + t) * N3 + myu;
      xg0[i] = q[0]; xg1[i] = q[512]; xg2[i] = q[1024];
    }

    if (t > 0) {   // wave-uniform poll: ONE coalesced LLC request per iteration
      const u32* c = &cnt[g * NS + (t - 1)];
      while (__hip_atomic_load(c, __ATOMIC_RELAXED,
                               __HIP_MEMORY_SCOPE_AGENT) != 32u) {}
      asm volatile("" ::: "memory");
    }

    // load all 16 A-slabs into registers (16 B per slab per lane, sc1)
    u64 alo[16], ahi[16];
    u64* hrow = (u64*)(hx + ((size_t)t * NB + (g << 4) + ar) * NU);
    #pragma unroll
    for (int ks = 0; ks < 16; ++ks) {
      const int qi = (ks << 3) + (kg << 1);
      alo[ks] = __hip_atomic_load(&hrow[qi],     __ATOMIC_RELAXED, __HIP_MEMORY_SCOPE_AGENT);
      ahi[ks] = __hip_atomic_load(&hrow[qi + 1], __ATOMIC_RELAXED, __HIP_MEMORY_SCOPE_AGENT);
    }

    // rp for my 16 units x 3 gates: 48 MFMAs, accumulators only
    f32x4 a0 = {0.f,0.f,0.f,0.f}, a1 = a0, a2 = a0;
    #pragma unroll
    for (int ks = 0; ks < 16; ++ks) {
      union { u64 q[2]; s16x8 v; } af;
      af.q[0] = alo[ks]; af.q[1] = ahi[ks];
      const int kb = (ks << 5) + (kg << 3);
      a0 = __builtin_amdgcn_mfma_f32_16x16x32_bf16(af.v, *(const s16x8*)&Rt[cb][kb],      a0, 0,0,0);
      a1 = __builtin_amdgcn_mfma_f32_16x16x32_bf16(af.v, *(const s16x8*)&Rt[cb + 16][kb], a1, 0,0,0);
      a2 = __builtin_amdgcn_mfma_f32_16x16x32_bf16(af.v, *(const s16x8*)&Rt[cb + 32][kb], a2, 0,0,0);
    }

    // gates straight from accumulators: D row = drow+i (batch), col = cu (unit)
    #pragma unroll
    for (int i = 0; i < 4; ++i) {
      const float z = 1.f / (1.f + __expf(-(xg0[i] + a0[i] + bz)));
      const float r = 1.f / (1.f + __expf(-(xg1[i] + a1[i] + br)));
      const float e = __expf(2.f * (xg2[i] + r * (a2[i] + bh)));
      const float hh = (e - 1.f) / (e + 1.f);     // tanh
      hr[i] = z * hr[i] + (1.f - z) * hh;
    }

    if (t < NS - 1) {   // signal path: hx stores -> vmcnt(0) -> counter add
      #pragma unroll
      for (int i = 0; i < 4; ++i)
        __hip_atomic_store(&hx[((size_t)(t + 1) * NB + (g << 4) + drow + i) * NU + myu],
                           f2bf(hr[i]), __ATOMIC_RELAXED, __HIP_MEMORY_SCOPE_AGENT);
      asm volatile("s_waitcnt vmcnt(0)" ::: "memory");
      if (lane == 0)
        __hip_atomic_fetch_add(&cnt[g * NS + t], 1u,
                               __ATOMIC_RELAXED, __HIP_MEMORY_SCOPE_AGENT);
    }

    // out stores AFTER the signal (drained by next step's vmcnt(0))
    #pragma unroll
    for (int i = 0; i < 4; ++i)
      out[((size_t)((g << 4) + drow + i) * NS + t) * NU + myu] = hr[i];
    if (t == NS - 1) {
      #pragma unroll
      for (int i = 0; i < 4; ++i)
        out[(size_t)NB * NS * NU + (size_t)((g << 4) + drow + i) * NU + myu] = hr[i];
    }
  }
}

extern "C" void kernel_launch(void* const* d_in, const int* in_sizes, int n_in,
                              void* d_out, int out_size, void* d_ws, size_t ws_size,
                              hipStream_t stream) {
  const int*   x      = (const int*)d_in[0];
  const float* hidden = (const float*)d_in[1];
  const float* emb    = (const float*)d_in[2];
  const float* W      = (const float*)d_in[3];
  const float* R      = (const float*)d_in[4];
  const float* bias   = (const float*)d_in[5];
  float* out = (float*)d_out;

  char* ws = (char*)d_ws;
  float* xp  = (float*)ws;                            // 50,331,648 B
  u16*   hx  = (u16*)(ws + 50331648);                 //  8,388,608 B (128 slots)
  u32*   cnt = (u32*)(ws + 50331648 + 8454144);       //      2,048 B

  init_kernel<<<NB, NU, 0, stream>>>(hidden, hx, cnt);
  dim3 gA(N3 / 64, (NB * NS) / 64);
  xproj_kernel<<<gA, 256, 0, stream>>>(x, emb, W, bias, xp);
  gru_scan_kernel<<<64, 128, 0, stream>>>(xp, hidden, R, bias, out, hx, cnt);
}